// Round 14
// baseline (882.809 us; speedup 1.0000x reference)
//
#include <hip/hip_runtime.h>

#define MDIM 16384
#define NDIM 4096
#define KDIM 4096
#define NT   64          // K-tiles of BK=64

typedef unsigned short u16;
typedef unsigned int   u32;
typedef __attribute__((ext_vector_type(8))) short bh8;    // 8 x bf16
typedef __attribute__((ext_vector_type(4))) float f32x4;
typedef __attribute__((ext_vector_type(4))) int   i32x4;

__device__ __forceinline__ u16 f2bf(float f) {
  u32 u = __builtin_bit_cast(u32, f);
  u = (u + 0x7fffu + ((u >> 16) & 1u)) >> 16;   // RNE
  return (u16)u;
}

__device__ __forceinline__ void gld16(const void* g, const void* lds) {
  __builtin_amdgcn_global_load_lds((const __attribute__((address_space(1))) u32*)g,
                                   (__attribute__((address_space(3))) u32*)lds, 16, 0, 0);
}

// ---------------- prepass 1: x fp32 -> bf16 ----------------
__global__ void cvt_x(const float* __restrict__ x, u16* __restrict__ xb) {
  size_t i = ((size_t)blockIdx.x * 256 + threadIdx.x) * 8;
  f32x4 a = *(const f32x4*)(x + i);
  f32x4 b = *(const f32x4*)(x + i + 4);
  bh8 o;
  o[0] = (short)f2bf(a[0]); o[1] = (short)f2bf(a[1]);
  o[2] = (short)f2bf(a[2]); o[3] = (short)f2bf(a[3]);
  o[4] = (short)f2bf(b[0]); o[5] = (short)f2bf(b[1]);
  o[6] = (short)f2bf(b[2]); o[7] = (short)f2bf(b[3]);
  *(bh8*)(xb + i) = o;
}

// ---------------- prepass 2: dequant W -> bf16 [4096][4096] ----------------
__global__ void deq_w(const int* __restrict__ qi, const void* __restrict__ nrm,
                      u16* __restrict__ wb) {
  __shared__ int s_q8, s_n32;
  if (threadIdx.x == 0) {
    int packed = 0;
    for (int t = 0; t < 64; ++t) { unsigned v = (unsigned)qi[t]; if (v > 15u) packed = 1; }
    int n32 = 0;
    const u16* h = (const u16*)nrm;
    for (int t = 0; t < 64; ++t) { u16 b = h[t]; if (b < 0x8000u && b > 0x3C00u) n32 = 1; }
    s_q8 = packed; s_n32 = n32;
  }
  __syncthreads();
  const bool q8 = (s_q8 != 0), n32 = (s_n32 != 0);

  int g = blockIdx.x * 256 + threadIdx.x;
  float s;
  if (n32) s = ((const float*)nrm)[g] * (1.0f / 15.0f);
  else {
    u16 hb = ((const u16*)nrm)[g];
    s = (float)__builtin_bit_cast(_Float16, hb) * (1.0f / 15.0f);
  }
  float q[16];
  if (q8) {
    i32x4 v = *(const i32x4*)((const unsigned char*)qi + (size_t)g * 16);
#pragma unroll
    for (int k = 0; k < 4; ++k) {
      int word = v[k];
      q[k*4+0] = (float)(word & 255);        q[k*4+1] = (float)((word >> 8) & 255);
      q[k*4+2] = (float)((word >> 16) & 255); q[k*4+3] = (float)((word >> 24) & 255);
    }
  } else {
    const i32x4* p = (const i32x4*)(qi + (size_t)g * 16);
#pragma unroll
    for (int k = 0; k < 4; ++k) {
      i32x4 v = p[k];
      q[k*4+0] = (float)v[0]; q[k*4+1] = (float)v[1];
      q[k*4+2] = (float)v[2]; q[k*4+3] = (float)v[3];
    }
  }
  bh8 o0, o1;
#pragma unroll
  for (int j = 0; j < 8; ++j) o0[j] = (short)f2bf(q[j] * s);
#pragma unroll
  for (int j = 0; j < 8; ++j) o1[j] = (short)f2bf(q[8 + j] * s);
  *(bh8*)(wb + (size_t)g * 16) = o0;
  *(bh8*)(wb + (size_t)g * 16 + 8) = o1;
}

// ---------------- 16-wave GEMM: 64x64/wave, 4 waves/SIMD ----------------
// 256x256 tile, BK=64, 16 waves (4Mx4N), per-wave 64x64 out, 16x16x32 MFMA.
// acc = 64 VGPR -> per-wave unified regs ~115 < 128 -> 4 waves/SIMD (50% occ).
// LDS (shorts): A: [buf(2)][half(2)][128 rows'][64 k] at 0..32767, B at 32768+;
// half = 16-row-block parity (global row = (r'>>4)*32 + h*16 + (r'&15));
// 16B chunks XOR-swizzled: stored chunk = c ^ (r16 & 7)  (R5-R12: conflicts 0).
// Staging: wave w writes rows r' in [w*8, w*8+8) of each half (1 gld16/half);
// source row = base + (w>>1)*32 + h*16 + (w&1)*8 + (l>>3), chunk (l&7)^(l>>3)
// (algebra: dest chunk l&7 == src ^ (r16&7) since r16&7 == l>>3).  Simple
// 2-barrier loop, depth-1 prefetch, per-wave vmcnt(4) drains current tile;
// cross-wave visibility: every wave waits vmcnt(4) before bar1 (R5 argument).
__global__ __launch_bounds__(1024, 4) void gemm16(const u16* __restrict__ A,
                                                  const u16* __restrict__ B,
                                                  const float* __restrict__ bias,
                                                  float* __restrict__ out) {
  __shared__ u16 lds[65536];
  const int tid = threadIdx.x;
  const int w = tid >> 6, l = tid & 63;
  const int wm = w >> 2, wn = w & 3;

  int bid = blockIdx.x;
  int wg = (bid & 7) * 128 + (bid >> 3);      // XCD-bijective (1024 % 8 == 0)
  const int bm = wg >> 4;                     // 0..63
  const int bn = wg & 15;                     // 0..15

  // staging lane constants
  const int cs8   = ((l & 7) ^ (l >> 3)) * 8;
  const int srow  = (w >> 1) * 32 + (w & 1) * 8 + (l >> 3);
  const u16* aS0 = A + (size_t)(bm * 256 + srow) * 4096 + cs8;        // h=0
  const u16* aS1 = A + (size_t)(bm * 256 + 16 + srow) * 4096 + cs8;   // h=1
  const u16* bS0 = B + (size_t)(bn * 256 + srow) * 4096 + cs8;
  const u16* bS1 = B + (size_t)(bn * 256 + 16 + srow) * 4096 + cs8;
  const int dstW = w * 512;                   // wave's 8-row slot in each half

  // fragment lane constants
  const int rl  = (l & 15) * 64;
  const int ck0 = ((l >> 4) ^ (l & 7)) * 8;        // kk=0 chunk offset
  const int ck1 = ((4 + (l >> 4)) ^ (l & 7)) * 8;  // kk=1

  f32x4 acc[4][4];
#pragma unroll
  for (int mi = 0; mi < 4; ++mi)
#pragma unroll
    for (int ni = 0; ni < 4; ++ni) acc[mi][ni] = (f32x4){0.f, 0.f, 0.f, 0.f};

  auto STG = [&](int buf, int kt) {           // whole K-tile: 4 gld16 per wave
    const int k = kt * 64;
    gld16(aS0 + k, &lds[(buf * 2 + 0) * 8192 + dstW]);
    gld16(aS1 + k, &lds[(buf * 2 + 1) * 8192 + dstW]);
    gld16(bS0 + k, &lds[32768 + (buf * 2 + 0) * 8192 + dstW]);
    gld16(bS1 + k, &lds[32768 + (buf * 2 + 1) * 8192 + dstW]);
  };

  auto COMPUTE = [&](int buf) {
#pragma unroll
    for (int kk = 0; kk < 2; ++kk) {
      const int ck = kk ? ck1 : ck0;
      bh8 af[4], bf[4];
#pragma unroll
      for (int mi = 0; mi < 4; ++mi) {
        const int G = wm * 4 + mi;            // 16-row block index (compile-time)
        af[mi] = *(const bh8*)&lds[(buf * 2 + (G & 1)) * 8192 + (G >> 1) * 1024 + rl + ck];
      }
#pragma unroll
      for (int ni = 0; ni < 4; ++ni) {
        const int G = wn * 4 + ni;
        bf[ni] = *(const bh8*)&lds[32768 + (buf * 2 + (G & 1)) * 8192 + (G >> 1) * 1024 + rl + ck];
      }
#pragma unroll
      for (int mi = 0; mi < 4; ++mi)
#pragma unroll
        for (int ni = 0; ni < 4; ++ni)
          acc[mi][ni] = __builtin_amdgcn_mfma_f32_16x16x32_bf16(af[mi], bf[ni],
                                                                acc[mi][ni], 0, 0, 0);
    }
  };

#define BAR asm volatile("" ::: "memory"); __builtin_amdgcn_s_barrier(); \
            asm volatile("" ::: "memory");

  STG(0, 0);                                  // prologue: tile 0 -> buf0
#pragma unroll 1
  for (int i = 0; i < NT / 2; ++i) {
    const int a = 2 * i;
    // tile a (buf0): stage a+1 -> buf1, drain tile a (4 newest stay in flight)
    STG(1, a + 1);
    asm volatile("s_waitcnt vmcnt(4)");
    BAR;
    COMPUTE(0);
    BAR;
    // tile a+1 (buf1): stage a+2 -> buf0 (a consumed), drain tile a+1
    if (a + 2 < NT) {
      STG(0, a + 2);
      asm volatile("s_waitcnt vmcnt(4)");
    } else {
      asm volatile("s_waitcnt vmcnt(0)");
    }
    BAR;
    COMPUTE(1);
    BAR;
  }
#undef BAR

  // epilogue: + bias, fp32 store. D layout: col=lane&15, row=(lane>>4)*4+reg
  const int col0 = bn * 256 + wn * 64 + (l & 15);
  const int row0 = bm * 256 + wm * 64 + (l >> 4) * 4;
#pragma unroll
  for (int ni = 0; ni < 4; ++ni) {
    float bv = bias[col0 + ni * 16];
#pragma unroll
    for (int mi = 0; mi < 4; ++mi) {
      size_t base = (size_t)(row0 + mi * 16) * 4096 + (size_t)(col0 + ni * 16);
#pragma unroll
      for (int rr = 0; rr < 4; ++rr)
        out[base + (size_t)rr * 4096] = acc[mi][ni][rr] + bv;
    }
  }
}

// ---------------- fallback 2-phase GEMM (ws too small for x-bf16): R1-verified ----------------
__global__ __launch_bounds__(512, 2) void gemm_fb(const float* __restrict__ Af32,
                                                  const u16* __restrict__ Wbf,
                                                  const float* __restrict__ bias,
                                                  float* __restrict__ out) {
  __shared__ u16 lds[65536];
  const int tid = threadIdx.x;
  const int w = tid >> 6, l = tid & 63;
  const int wm = w >> 2, wn = w & 3;
  int bid = blockIdx.x;
  int wg = (bid & 7) * 128 + (bid >> 3);
  const int bm = wg >> 4, bn = wg & 15;

  int srcOffB[4], srcOffA32[4], dstSwzA[4];
#pragma unroll
  for (int j = 0; j < 4; ++j) {
    int ci = (w * 4 + j) * 64 + l;
    int r = ci >> 3, c = ci & 7;
    int cs = c ^ (r & 7);
    srcOffB[j]   = (bn * 256 + r) * 4096 + cs * 8;
    srcOffA32[j] = (bm * 256 + r) * 4096 + c * 8;
    dstSwzA[j]   = r * 64 + cs * 8;
  }
  const int ar = wm * 128 + (l & 15);
  const int br = wn * 64 + (l & 15);
  const int swz0 = (((l >> 4) + 0) ^ (l & 7)) * 8;
  const int swz1 = (((l >> 4) + 4) ^ (l & 7)) * 8;
  const int aoff0 = ar * 64 + swz0, aoff1 = ar * 64 + swz1;
  const int boff0 = 32768 + br * 64 + swz0, boff1 = 32768 + br * 64 + swz1;

  f32x4 acc[8][4];
#pragma unroll
  for (int mi = 0; mi < 8; ++mi)
#pragma unroll
    for (int ni = 0; ni < 4; ++ni) acc[mi][ni] = (f32x4){0.f, 0.f, 0.f, 0.f};

  auto STAGE = [&](int bufb, int kt) {
    const int kof = kt * 64;
#pragma unroll
    for (int j = 0; j < 4; ++j) {
      gld16(Wbf + srcOffB[j] + kof, &lds[32768 + bufb * 16384 + (w * 4 + j) * 512]);
      const float* p = Af32 + srcOffA32[j] + kof;
      f32x4 v0 = *(const f32x4*)p;
      f32x4 v1 = *(const f32x4*)(p + 4);
      bh8 o;
      o[0] = (short)f2bf(v0[0]); o[1] = (short)f2bf(v0[1]);
      o[2] = (short)f2bf(v0[2]); o[3] = (short)f2bf(v0[3]);
      o[4] = (short)f2bf(v1[0]); o[5] = (short)f2bf(v1[1]);
      o[6] = (short)f2bf(v1[2]); o[7] = (short)f2bf(v1[3]);
      *(bh8*)&lds[bufb * 16384 + dstSwzA[j]] = o;
    }
  };
  auto COMPUTE = [&](int bufb) {
    const int ab = bufb * 16384;
#pragma unroll
    for (int kk = 0; kk < 2; ++kk) {
      const int ao = ab + (kk ? aoff1 : aoff0);
      const int bo = ab + (kk ? boff1 : boff0);
      bh8 afr[8], bfr[4];
#pragma unroll
      for (int mi = 0; mi < 8; ++mi) afr[mi] = *(const bh8*)&lds[ao + mi * 1024];
#pragma unroll
      for (int ni = 0; ni < 4; ++ni) bfr[ni] = *(const bh8*)&lds[bo + ni * 1024];
#pragma unroll
      for (int mi = 0; mi < 8; ++mi)
#pragma unroll
        for (int ni = 0; ni < 4; ++ni)
          acc[mi][ni] = __builtin_amdgcn_mfma_f32_16x16x32_bf16(afr[mi], bfr[ni],
                                                                acc[mi][ni], 0, 0, 0);
    }
  };

  int buf = 0;
  STAGE(0, 0);
  __syncthreads();
  for (int kt = 0; kt < NT - 1; ++kt) {
    STAGE(buf ^ 1, kt + 1);
    COMPUTE(buf);
    __syncthreads();
    buf ^= 1;
  }
  COMPUTE(buf);

  const int col0 = bn * 256 + wn * 64 + (l & 15);
  const int row0 = bm * 256 + wm * 128 + (l >> 4) * 4;
#pragma unroll
  for (int ni = 0; ni < 4; ++ni) {
    float bv = bias[col0 + ni * 16];
#pragma unroll
    for (int mi = 0; mi < 8; ++mi) {
      size_t base = (size_t)(row0 + mi * 16) * 4096 + (size_t)(col0 + ni * 16);
#pragma unroll
      for (int rr = 0; rr < 4; ++rr)
        out[base + (size_t)rr * 4096] = acc[mi][ni][rr] + bv;
    }
  }
}

extern "C" void kernel_launch(void* const* d_in, const int* in_sizes, int n_in,
                              void* d_out, int out_size, void* d_ws, size_t ws_size,
                              hipStream_t stream) {
  const float* x    = (const float*)d_in[0];
  const int*   wq   = (const int*)d_in[1];
  const void*  wn   = d_in[2];
  const float* bias = (const float*)d_in[3];
  float*       out  = (float*)d_out;

  const size_t needA = (size_t)MDIM * KDIM * 2;
  const size_t needW = (size_t)NDIM * KDIM * 2;

  if (ws_size >= needA + needW) {
    u16* xbf = (u16*)d_ws;
    u16* wbf = (u16*)((char*)d_ws + needA);
    cvt_x<<<dim3(32768), dim3(256), 0, stream>>>(x, xbf);
    deq_w<<<dim3(4096), dim3(256), 0, stream>>>(wq, wn, wbf);
    gemm16<<<dim3(1024), dim3(1024), 0, stream>>>(xbf, wbf, bias, out);
  } else if (ws_size >= needW) {
    u16* wbf = (u16*)d_ws;
    deq_w<<<dim3(4096), dim3(256), 0, stream>>>(wq, wn, wbf);
    gemm_fb<<<dim3(1024), dim3(512), 0, stream>>>(x, wbf, bias, out);
  }
}

// Round 15
// 629.219 us; speedup vs baseline: 1.4030x; 1.4030x over previous
//
#include <hip/hip_runtime.h>

#define MDIM 16384
#define NDIM 4096
#define KDIM 4096
#define NT   64          // K-tiles of BK=64

typedef unsigned short u16;
typedef unsigned int   u32;
typedef __attribute__((ext_vector_type(8))) short bh8;    // 8 x bf16
typedef __attribute__((ext_vector_type(4))) float f32x4;
typedef __attribute__((ext_vector_type(4))) int   i32x4;

__device__ __forceinline__ u16 f2bf(float f) {
  u32 u = __builtin_bit_cast(u32, f);
  u = (u + 0x7fffu + ((u >> 16) & 1u)) >> 16;   // RNE
  return (u16)u;
}

__device__ __forceinline__ void gld16(const void* g, const void* lds) {
  __builtin_amdgcn_global_load_lds((const __attribute__((address_space(1))) u32*)g,
                                   (__attribute__((address_space(3))) u32*)lds, 16, 0, 0);
}

// ---------------- prepass 1: x fp32 -> bf16 ----------------
__global__ void cvt_x(const float* __restrict__ x, u16* __restrict__ xb) {
  size_t i = ((size_t)blockIdx.x * 256 + threadIdx.x) * 8;
  f32x4 a = *(const f32x4*)(x + i);
  f32x4 b = *(const f32x4*)(x + i + 4);
  bh8 o;
  o[0] = (short)f2bf(a[0]); o[1] = (short)f2bf(a[1]);
  o[2] = (short)f2bf(a[2]); o[3] = (short)f2bf(a[3]);
  o[4] = (short)f2bf(b[0]); o[5] = (short)f2bf(b[1]);
  o[6] = (short)f2bf(b[2]); o[7] = (short)f2bf(b[3]);
  *(bh8*)(xb + i) = o;
}

// ---------------- prepass 2: dequant W -> bf16 [4096][4096] ----------------
__global__ void deq_w(const int* __restrict__ qi, const void* __restrict__ nrm,
                      u16* __restrict__ wb) {
  __shared__ int s_q8, s_n32;
  if (threadIdx.x == 0) {
    int packed = 0;
    for (int t = 0; t < 64; ++t) { unsigned v = (unsigned)qi[t]; if (v > 15u) packed = 1; }
    int n32 = 0;
    const u16* h = (const u16*)nrm;
    for (int t = 0; t < 64; ++t) { u16 b = h[t]; if (b < 0x8000u && b > 0x3C00u) n32 = 1; }
    s_q8 = packed; s_n32 = n32;
  }
  __syncthreads();
  const bool q8 = (s_q8 != 0), n32 = (s_n32 != 0);

  int g = blockIdx.x * 256 + threadIdx.x;
  float s;
  if (n32) s = ((const float*)nrm)[g] * (1.0f / 15.0f);
  else {
    u16 hb = ((const u16*)nrm)[g];
    s = (float)__builtin_bit_cast(_Float16, hb) * (1.0f / 15.0f);
  }
  float q[16];
  if (q8) {
    i32x4 v = *(const i32x4*)((const unsigned char*)qi + (size_t)g * 16);
#pragma unroll
    for (int k = 0; k < 4; ++k) {
      int word = v[k];
      q[k*4+0] = (float)(word & 255);        q[k*4+1] = (float)((word >> 8) & 255);
      q[k*4+2] = (float)((word >> 16) & 255); q[k*4+3] = (float)((word >> 24) & 255);
    }
  } else {
    const i32x4* p = (const i32x4*)(qi + (size_t)g * 16);
#pragma unroll
    for (int k = 0; k < 4; ++k) {
      i32x4 v = p[k];
      q[k*4+0] = (float)v[0]; q[k*4+1] = (float)v[1];
      q[k*4+2] = (float)v[2]; q[k*4+3] = (float)v[3];
    }
  }
  bh8 o0, o1;
#pragma unroll
  for (int j = 0; j < 8; ++j) o0[j] = (short)f2bf(q[j] * s);
#pragma unroll
  for (int j = 0; j < 8; ++j) o1[j] = (short)f2bf(q[8 + j] * s);
  *(bh8*)(wb + (size_t)g * 16) = o0;
  *(bh8*)(wb + (size_t)g * 16 + 8) = o1;
}

// ---------------- 16-wave GEMM: 64x64/wave, 4 waves/SIMD, arch-VGPR diet ----------------
// 256x256 tile, BK=64, 16 waves (4Mx4N), per-wave 64x64 out, 16x16x32 MFMA.
// acc = 64 (AGPR-region); arch target <=64: 4 self-incrementing src pointers
// (8 VGPR), 4 precomputed LDS frag addrs (consts folded into ds_read offsets),
// frag liveness capped at 32 by sched_barrier(0) between kk iterations.
// LDS/staging/swizzle/read algebra byte-identical to R14 (HW-verified, absmax 0.5,
// conflicts 0): stored chunk = c ^ (r16 & 7); wave w stages rows [w*8,w*8+8) per
// half; simple 2-barrier loop, depth-1 prefetch, per-wave vmcnt(4).
__global__ __launch_bounds__(1024, 4) void gemm16(const u16* __restrict__ A,
                                                  const u16* __restrict__ B,
                                                  const float* __restrict__ bias,
                                                  float* __restrict__ out) {
  __shared__ u16 lds[65536];
  const int tid = threadIdx.x;
  const int w = tid >> 6, l = tid & 63;
  const int wm = w >> 2, wn = w & 3;

  int bid = blockIdx.x;
  int wg = (bid & 7) * 128 + (bid >> 3);      // XCD-bijective (1024 % 8 == 0)
  const int bm = wg >> 4;                     // 0..63
  const int bn = wg & 15;                     // 0..15

  // staging lane constants (R14-verified algebra); pointers self-increment
  const int cs8  = ((l & 7) ^ (l >> 3)) * 8;
  const int srow = (w >> 1) * 32 + (w & 1) * 8 + (l >> 3);
  const u16* aS0 = A + (size_t)(bm * 256 + srow) * 4096 + cs8;        // h=0
  const u16* aS1 = A + (size_t)(bm * 256 + 16 + srow) * 4096 + cs8;   // h=1
  const u16* bS0 = B + (size_t)(bn * 256 + srow) * 4096 + cs8;
  const u16* bS1 = B + (size_t)(bn * 256 + 16 + srow) * 4096 + cs8;
  const int dstW = w * 512;                   // wave's 8-row slot in each half

  // fragment lane constants: 4 precomputed addrs; all buf/mi/ni terms are
  // compile-time consts folded into the 16-bit ds_read offset field.
  const int rl = (l & 15) * 64;
  const int a0 = wm * 2048 + rl + ((l >> 4) ^ (l & 7)) * 8;
  const int a1 = wm * 2048 + rl + ((4 + (l >> 4)) ^ (l & 7)) * 8;
  const int b0 = 32768 + wn * 2048 + rl + ((l >> 4) ^ (l & 7)) * 8;
  const int b1 = 32768 + wn * 2048 + rl + ((4 + (l >> 4)) ^ (l & 7)) * 8;

  f32x4 acc[4][4];
#pragma unroll
  for (int mi = 0; mi < 4; ++mi)
#pragma unroll
    for (int ni = 0; ni < 4; ++ni) acc[mi][ni] = (f32x4){0.f, 0.f, 0.f, 0.f};

  auto STG = [&](int buf) {                   // stage next tile; bump pointers
    gld16(aS0, &lds[(buf * 2 + 0) * 8192 + dstW]);
    gld16(aS1, &lds[(buf * 2 + 1) * 8192 + dstW]);
    gld16(bS0, &lds[32768 + (buf * 2 + 0) * 8192 + dstW]);
    gld16(bS1, &lds[32768 + (buf * 2 + 1) * 8192 + dstW]);
    aS0 += 64; aS1 += 64; bS0 += 64; bS1 += 64;   // advance one K-tile
  };

  auto COMPUTE = [&](int buf) {
#pragma unroll
    for (int kk = 0; kk < 2; ++kk) {
      const int av = kk ? a1 : a0, bv = kk ? b1 : b0;
      bh8 af[4], bf[4];
#pragma unroll
      for (int mi = 0; mi < 4; ++mi)    // (mi&1)=half parity, (mi>>1)=1KB group
        af[mi] = *(const bh8*)&lds[(buf * 2 + (mi & 1)) * 8192 + (mi >> 1) * 1024 + av];
#pragma unroll
      for (int ni = 0; ni < 4; ++ni)
        bf[ni] = *(const bh8*)&lds[(buf * 2 + (ni & 1)) * 8192 + (ni >> 1) * 1024 + bv];
#pragma unroll
      for (int mi = 0; mi < 4; ++mi)
#pragma unroll
        for (int ni = 0; ni < 4; ++ni)
          acc[mi][ni] = __builtin_amdgcn_mfma_f32_16x16x32_bf16(af[mi], bf[ni],
                                                                acc[mi][ni], 0, 0, 0);
      __builtin_amdgcn_sched_barrier(0);    // cap frag liveness at one kk set
    }
  };

#define BAR asm volatile("" ::: "memory"); __builtin_amdgcn_s_barrier(); \
            asm volatile("" ::: "memory");

  STG(0);                                     // tile 0 -> buf0
#pragma unroll 1
  for (int i = 0; i < NT - 2; i += 2) {
    STG(1);                                   // tile i+1 -> buf1
    asm volatile("s_waitcnt vmcnt(4)");       // tile i landed
    BAR;
    COMPUTE(0);
    BAR;
    STG(0);                                   // tile i+2 -> buf0
    asm volatile("s_waitcnt vmcnt(4)");       // tile i+1 landed
    BAR;
    COMPUTE(1);
    BAR;
  }
  // tail: tiles NT-2 (buf0), NT-1 (buf1)
  STG(1);                                     // tile 63 -> buf1
  asm volatile("s_waitcnt vmcnt(4)");
  BAR;
  COMPUTE(0);
  BAR;
  asm volatile("s_waitcnt vmcnt(0)");
  BAR;
  COMPUTE(1);
#undef BAR

  // epilogue: + bias, fp32 store. D layout: col=lane&15, row=(lane>>4)*4+reg
  const int col0 = bn * 256 + wn * 64 + (l & 15);
  const int row0 = bm * 256 + wm * 64 + (l >> 4) * 4;
#pragma unroll
  for (int ni = 0; ni < 4; ++ni) {
    float bv = bias[col0 + ni * 16];
#pragma unroll
    for (int mi = 0; mi < 4; ++mi) {
      size_t base = (size_t)(row0 + mi * 16) * 4096 + (size_t)(col0 + ni * 16);
#pragma unroll
      for (int rr = 0; rr < 4; ++rr)
        out[base + (size_t)rr * 4096] = acc[mi][ni][rr] + bv;
    }
  }
}

// ---------------- fallback 2-phase GEMM (ws too small for x-bf16): R1-verified ----------------
__global__ __launch_bounds__(512, 2) void gemm_fb(const float* __restrict__ Af32,
                                                  const u16* __restrict__ Wbf,
                                                  const float* __restrict__ bias,
                                                  float* __restrict__ out) {
  __shared__ u16 lds[65536];
  const int tid = threadIdx.x;
  const int w = tid >> 6, l = tid & 63;
  const int wm = w >> 2, wn = w & 3;
  int bid = blockIdx.x;
  int wg = (bid & 7) * 128 + (bid >> 3);
  const int bm = wg >> 4, bn = wg & 15;

  int srcOffB[4], srcOffA32[4], dstSwzA[4];
#pragma unroll
  for (int j = 0; j < 4; ++j) {
    int ci = (w * 4 + j) * 64 + l;
    int r = ci >> 3, c = ci & 7;
    int cs = c ^ (r & 7);
    srcOffB[j]   = (bn * 256 + r) * 4096 + cs * 8;
    srcOffA32[j] = (bm * 256 + r) * 4096 + c * 8;
    dstSwzA[j]   = r * 64 + cs * 8;
  }
  const int ar = wm * 128 + (l & 15);
  const int br = wn * 64 + (l & 15);
  const int swz0 = (((l >> 4) + 0) ^ (l & 7)) * 8;
  const int swz1 = (((l >> 4) + 4) ^ (l & 7)) * 8;
  const int aoff0 = ar * 64 + swz0, aoff1 = ar * 64 + swz1;
  const int boff0 = 32768 + br * 64 + swz0, boff1 = 32768 + br * 64 + swz1;

  f32x4 acc[8][4];
#pragma unroll
  for (int mi = 0; mi < 8; ++mi)
#pragma unroll
    for (int ni = 0; ni < 4; ++ni) acc[mi][ni] = (f32x4){0.f, 0.f, 0.f, 0.f};

  auto STAGE = [&](int bufb, int kt) {
    const int kof = kt * 64;
#pragma unroll
    for (int j = 0; j < 4; ++j) {
      gld16(Wbf + srcOffB[j] + kof, &lds[32768 + bufb * 16384 + (w * 4 + j) * 512]);
      const float* p = Af32 + srcOffA32[j] + kof;
      f32x4 v0 = *(const f32x4*)p;
      f32x4 v1 = *(const f32x4*)(p + 4);
      bh8 o;
      o[0] = (short)f2bf(v0[0]); o[1] = (short)f2bf(v0[1]);
      o[2] = (short)f2bf(v0[2]); o[3] = (short)f2bf(v0[3]);
      o[4] = (short)f2bf(v1[0]); o[5] = (short)f2bf(v1[1]);
      o[6] = (short)f2bf(v1[2]); o[7] = (short)f2bf(v1[3]);
      *(bh8*)&lds[bufb * 16384 + dstSwzA[j]] = o;
    }
  };
  auto COMPUTE = [&](int bufb) {
    const int ab = bufb * 16384;
#pragma unroll
    for (int kk = 0; kk < 2; ++kk) {
      const int ao = ab + (kk ? aoff1 : aoff0);
      const int bo = ab + (kk ? boff1 : boff0);
      bh8 afr[8], bfr[4];
#pragma unroll
      for (int mi = 0; mi < 8; ++mi) afr[mi] = *(const bh8*)&lds[ao + mi * 1024];
#pragma unroll
      for (int ni = 0; ni < 4; ++ni) bfr[ni] = *(const bh8*)&lds[bo + ni * 1024];
#pragma unroll
      for (int mi = 0; mi < 8; ++mi)
#pragma unroll
        for (int ni = 0; ni < 4; ++ni)
          acc[mi][ni] = __builtin_amdgcn_mfma_f32_16x16x32_bf16(afr[mi], bfr[ni],
                                                                acc[mi][ni], 0, 0, 0);
    }
  };

  int buf = 0;
  STAGE(0, 0);
  __syncthreads();
  for (int kt = 0; kt < NT - 1; ++kt) {
    STAGE(buf ^ 1, kt + 1);
    COMPUTE(buf);
    __syncthreads();
    buf ^= 1;
  }
  COMPUTE(buf);

  const int col0 = bn * 256 + wn * 64 + (l & 15);
  const int row0 = bm * 256 + wm * 128 + (l >> 4) * 4;
#pragma unroll
  for (int ni = 0; ni < 4; ++ni) {
    float bv = bias[col0 + ni * 16];
#pragma unroll
    for (int mi = 0; mi < 8; ++mi) {
      size_t base = (size_t)(row0 + mi * 16) * 4096 + (size_t)(col0 + ni * 16);
#pragma unroll
      for (int rr = 0; rr < 4; ++rr)
        out[base + (size_t)rr * 4096] = acc[mi][ni][rr] + bv;
    }
  }
}

extern "C" void kernel_launch(void* const* d_in, const int* in_sizes, int n_in,
                              void* d_out, int out_size, void* d_ws, size_t ws_size,
                              hipStream_t stream) {
  const float* x    = (const float*)d_in[0];
  const int*   wq   = (const int*)d_in[1];
  const void*  wn   = d_in[2];
  const float* bias = (const float*)d_in[3];
  float*       out  = (float*)d_out;

  const size_t needA = (size_t)MDIM * KDIM * 2;
  const size_t needW = (size_t)NDIM * KDIM * 2;

  if (ws_size >= needA + needW) {
    u16* xbf = (u16*)d_ws;
    u16* wbf = (u16*)((char*)d_ws + needA);
    cvt_x<<<dim3(32768), dim3(256), 0, stream>>>(x, xbf);
    deq_w<<<dim3(4096), dim3(256), 0, stream>>>(wq, wn, wbf);
    gemm16<<<dim3(1024), dim3(1024), 0, stream>>>(xbf, wbf, bias, out);
  } else if (ws_size >= needW) {
    u16* wbf = (u16*)d_ws;
    deq_w<<<dim3(4096), dim3(256), 0, stream>>>(wq, wn, wbf);
    gemm_fb<<<dim3(1024), dim3(512), 0, stream>>>(x, wbf, bias, out);
  }
}

// Round 16
// 538.651 us; speedup vs baseline: 1.6389x; 1.1681x over previous
//
#include <hip/hip_runtime.h>

#define MDIM 16384
#define NDIM 4096
#define KDIM 4096
#define NT   64          // K-tiles of BK=64

typedef unsigned short u16;
typedef unsigned int   u32;
typedef __attribute__((ext_vector_type(8))) short bh8;    // 8 x bf16
typedef __attribute__((ext_vector_type(4))) float f32x4;
typedef __attribute__((ext_vector_type(4))) int   i32x4;

__device__ __forceinline__ u16 f2bf(float f) {
  u32 u = __builtin_bit_cast(u32, f);
  u = (u + 0x7fffu + ((u >> 16) & 1u)) >> 16;   // RNE
  return (u16)u;
}

__device__ __forceinline__ void gld16(const void* g, const void* lds) {
  __builtin_amdgcn_global_load_lds((const __attribute__((address_space(1))) u32*)g,
                                   (__attribute__((address_space(3))) u32*)lds, 16, 0, 0);
}

// ---------------- prepass 1: x fp32 -> bf16 ----------------
__global__ void cvt_x(const float* __restrict__ x, u16* __restrict__ xb) {
  size_t i = ((size_t)blockIdx.x * 256 + threadIdx.x) * 8;
  f32x4 a = *(const f32x4*)(x + i);
  f32x4 b = *(const f32x4*)(x + i + 4);
  bh8 o;
  o[0] = (short)f2bf(a[0]); o[1] = (short)f2bf(a[1]);
  o[2] = (short)f2bf(a[2]); o[3] = (short)f2bf(a[3]);
  o[4] = (short)f2bf(b[0]); o[5] = (short)f2bf(b[1]);
  o[6] = (short)f2bf(b[2]); o[7] = (short)f2bf(b[3]);
  *(bh8*)(xb + i) = o;
}

// ---------------- prepass 2: dequant W -> bf16 [4096][4096] ----------------
__global__ void deq_w(const int* __restrict__ qi, const void* __restrict__ nrm,
                      u16* __restrict__ wb) {
  __shared__ int s_q8, s_n32;
  if (threadIdx.x == 0) {
    int packed = 0;
    for (int t = 0; t < 64; ++t) { unsigned v = (unsigned)qi[t]; if (v > 15u) packed = 1; }
    int n32 = 0;
    const u16* h = (const u16*)nrm;
    for (int t = 0; t < 64; ++t) { u16 b = h[t]; if (b < 0x8000u && b > 0x3C00u) n32 = 1; }
    s_q8 = packed; s_n32 = n32;
  }
  __syncthreads();
  const bool q8 = (s_q8 != 0), n32 = (s_n32 != 0);

  int g = blockIdx.x * 256 + threadIdx.x;
  float s;
  if (n32) s = ((const float*)nrm)[g] * (1.0f / 15.0f);
  else {
    u16 hb = ((const u16*)nrm)[g];
    s = (float)__builtin_bit_cast(_Float16, hb) * (1.0f / 15.0f);
  }
  float q[16];
  if (q8) {
    i32x4 v = *(const i32x4*)((const unsigned char*)qi + (size_t)g * 16);
#pragma unroll
    for (int k = 0; k < 4; ++k) {
      int word = v[k];
      q[k*4+0] = (float)(word & 255);        q[k*4+1] = (float)((word >> 8) & 255);
      q[k*4+2] = (float)((word >> 16) & 255); q[k*4+3] = (float)((word >> 24) & 255);
    }
  } else {
    const i32x4* p = (const i32x4*)(qi + (size_t)g * 16);
#pragma unroll
    for (int k = 0; k < 4; ++k) {
      i32x4 v = p[k];
      q[k*4+0] = (float)v[0]; q[k*4+1] = (float)v[1];
      q[k*4+2] = (float)v[2]; q[k*4+3] = (float)v[3];
    }
  }
  bh8 o0, o1;
#pragma unroll
  for (int j = 0; j < 8; ++j) o0[j] = (short)f2bf(q[j] * s);
#pragma unroll
  for (int j = 0; j < 8; ++j) o1[j] = (short)f2bf(q[8 + j] * s);
  *(bh8*)(wb + (size_t)g * 16) = o0;
  *(bh8*)(wb + (size_t)g * 16 + 8) = o1;
}

// ---------------- 8-phase GEMM (R12 final): R5 data-path + same-register B re-read ----------------
// 256x256 tile, BK=64, 8 waves (2Mx4N), per-wave 128x64 out, 16x16x32 MFMA.
// LDS (shorts): A: [buf(2)][half(2)][128 rows][64 k] at 0..32767, B same at 32768+;
// half = 16-row-block parity; 16B chunks XOR-swizzled: c' = c ^ (row & 7).
// Measured (R12): GEMM 475us, MfmaUtil 53-54%, conflicts 0, VGPR 128, absmax 0.5.
// B frag set bf_ single-buffered and re-read for the next tile in the p4/p8
// post-barrier windows AFTER its last consuming MFMA cluster (sched_barrier(0)
// pins the reads below the cluster). Staging calendar + vmcnt: tile-b's B slots
// drained by vmcnt(6)@p4 before RDB(1); next-a's by vmcnt(8)@p8 before RDB(0).
__global__ __launch_bounds__(512, 2) void gemm8(const u16* __restrict__ A,
                                                const u16* __restrict__ B,
                                                const float* __restrict__ bias,
                                                float* __restrict__ out) {
  __shared__ u16 lds[65536];
  const int tid = threadIdx.x;
  const int w = tid >> 6, l = tid & 63;
  const int wm = w >> 2, wn = w & 3;

  int bid = blockIdx.x;
  int wg = (bid & 7) * 128 + (bid >> 3);      // XCD-bijective (1024 % 8 == 0)
  const int bm = wg >> 4;                     // 0..63
  const int bn = wg & 15;                     // 0..15

  // staging lane constants (contiguous 128B row-segments, pre-swizzled source)
  const int cs8  = ((l & 7) ^ (l >> 3)) * 8;
  const u16* aSrc = A + (size_t)(bm * 256 + w * 32 + (l >> 3)) * 4096 + cs8;
  const u16* bSrc = B + (size_t)(bn * 256 + w * 32 + (l >> 3)) * 4096 + cs8;

  // fragment lane constants
  const int fr  = (l & 15) * 64;
  const int sz0 = ((l >> 4) ^ (l & 7)) * 8;
  const int sz1 = ((4 + (l >> 4)) ^ (l & 7)) * 8;

  f32x4 acc[8][4];
#pragma unroll
  for (int mi = 0; mi < 8; ++mi)
#pragma unroll
    for (int ni = 0; ni < 4; ++ni) acc[mi][ni] = (f32x4){0.f, 0.f, 0.f, 0.f};

  bh8 aX[2][2], aY[2][2];        // A m-block frag double-buffer (16 VGPR each)
  bh8 bf_[4][2];                 // B frag set, SINGLE buffer (32 VGPR)

  auto STG = [&](int op, int h, int kt) {     // one op-half = 2 x global_load_lds
    const u16* s = (op ? bSrc : aSrc) + h * 65536 + kt * 64;
    int d = (op ? 32768 : 0) + ((kt & 1) * 2 + h) * 8192 + w * 1024;
    gld16(s,         &lds[d]);
    gld16(s + 32768, &lds[d + 512]);
  };
  auto RDA = [&](int buf, int mb, bh8 (&aa)[2][2]) {  // one m-block: 4 ds_read_b128
#pragma unroll
    for (int q = 0; q < 2; ++q) {             // mi = mb*2+q; half = q
      int base = (buf * 2 + q) * 8192 + (wm * 4 + mb) * 1024 + fr;
      aa[q][0] = *(const bh8*)&lds[base + sz0];
      aa[q][1] = *(const bh8*)&lds[base + sz1];
    }
  };
  auto RDB = [&](int buf) {                   // all 4 n-frags: 8 ds_read_b128
#pragma unroll
    for (int r = 0; r < 4; ++r) {             // half = r&1
      int base = 32768 + (buf * 2 + (r & 1)) * 8192 + (wn * 2 + (r >> 1)) * 1024 + fr;
      bf_[r][0] = *(const bh8*)&lds[base + sz0];
      bf_[r][1] = *(const bh8*)&lds[base + sz1];
    }
  };
  auto MMB = [&](int mb, bh8 (&aa)[2][2]) {   // 16 MFMA on bf_
    __builtin_amdgcn_s_setprio(1);
#pragma unroll
    for (int kk = 0; kk < 2; ++kk)
#pragma unroll
      for (int q = 0; q < 2; ++q)
#pragma unroll
        for (int r = 0; r < 4; ++r)
          acc[mb*2+q][r] = __builtin_amdgcn_mfma_f32_16x16x32_bf16(
              aa[q][kk], bf_[r][kk], acc[mb*2+q][r], 0, 0, 0);
    __builtin_amdgcn_s_setprio(0);
  };

#define BAR1 asm volatile("" ::: "memory"); __builtin_amdgcn_s_barrier(); \
             asm volatile("" ::: "memory");
#define BAR2 asm volatile("" ::: "memory"); __builtin_amdgcn_s_barrier();
#define SBAR __builtin_amdgcn_sched_barrier(0);

  // prologue: t0 + t1 fully staged (16 loads); vmcnt(8): t0 landed, t1 in flight
  STG(1, 0, 0); STG(1, 1, 0); STG(0, 0, 0); STG(0, 1, 0);
  STG(1, 0, 1); STG(1, 1, 1); STG(0, 0, 1); STG(0, 1, 1);
  asm volatile("s_waitcnt vmcnt(8)");
  BAR1;
  RDA(0, 0, aX); RDB(0);                      // frags for p1 (tile 0)

#pragma unroll 1
  for (int i = 0; i < NT / 2 - 1; ++i) {
    const int c = 2 * i + 2, d = 2 * i + 3;
    // p1
    RDA(0, 1, aY);
    BAR1; MMB(0, aX); BAR2;
    // p2
    RDA(0, 2, aX); STG(1, 0, c);
    BAR1; MMB(1, aY); BAR2;
    // p3
    RDA(0, 3, aY); STG(1, 1, c);
    BAR1; MMB(2, aX); BAR2;
    // p4: drain tile b; last use of tile-a's bf_ -> re-read tile-b's B after it
    STG(0, 0, c); asm volatile("s_waitcnt vmcnt(6)");
    BAR1; RDA(1, 0, aX); MMB(3, aY); SBAR; RDB(1); BAR2;
    // p5
    RDA(1, 1, aY); STG(0, 1, c);
    BAR1; MMB(0, aX); BAR2;
    // p6
    RDA(1, 2, aX); STG(1, 0, d);
    BAR1; MMB(1, aY); BAR2;
    // p7
    RDA(1, 3, aY); STG(1, 1, d);
    BAR1; MMB(2, aX); BAR2;
    // p8: drain tile c; last use of tile-b's bf_ -> re-read next-a's B after it
    STG(0, 0, d); STG(0, 1, d); asm volatile("s_waitcnt vmcnt(8)");
    BAR1; RDA(0, 0, aX); MMB(3, aY); SBAR; RDB(0); BAR2;
  }
  // peeled final iteration: a=62 (buf0), b=63 (buf1); no staging
  RDA(0, 1, aY);
  BAR1; MMB(0, aX); BAR2;
  RDA(0, 2, aX);
  BAR1; MMB(1, aY); BAR2;
  RDA(0, 3, aY);
  BAR1; MMB(2, aX); BAR2;
  asm volatile("s_waitcnt vmcnt(0)");
  BAR1; RDA(1, 0, aX); MMB(3, aY); SBAR; RDB(1); BAR2;
  RDA(1, 1, aY);
  BAR1; MMB(0, aX); BAR2;
  RDA(1, 2, aX);
  BAR1; MMB(1, aY); BAR2;
  RDA(1, 3, aY);
  BAR1; MMB(2, aX); BAR2;
  BAR1; MMB(3, aY);
#undef BAR1
#undef BAR2
#undef SBAR

  // epilogue: + bias, fp32 store. D layout: col=lane&15, row=(lane>>4)*4+reg
  const int col0 = bn * 256 + wn * 64 + (l & 15);
  const int row0 = bm * 256 + wm * 128 + (l >> 4) * 4;
#pragma unroll
  for (int ni = 0; ni < 4; ++ni) {
    float bv = bias[col0 + ni * 16];
#pragma unroll
    for (int mi = 0; mi < 8; ++mi) {
      size_t base = (size_t)(row0 + mi * 16) * 4096 + (size_t)(col0 + ni * 16);
#pragma unroll
      for (int rr = 0; rr < 4; ++rr)
        out[base + (size_t)rr * 4096] = acc[mi][ni][rr] + bv;
    }
  }
}

// ---------------- fallback 2-phase GEMM (ws too small for x-bf16): R1-verified ----------------
__global__ __launch_bounds__(512, 2) void gemm_fb(const float* __restrict__ Af32,
                                                  const u16* __restrict__ Wbf,
                                                  const float* __restrict__ bias,
                                                  float* __restrict__ out) {
  __shared__ u16 lds[65536];
  const int tid = threadIdx.x;
  const int w = tid >> 6, l = tid & 63;
  const int wm = w >> 2, wn = w & 3;
  int bid = blockIdx.x;
  int wg = (bid & 7) * 128 + (bid >> 3);
  const int bm = wg >> 4, bn = wg & 15;

  int srcOffB[4], srcOffA32[4], dstSwzA[4];
#pragma unroll
  for (int j = 0; j < 4; ++j) {
    int ci = (w * 4 + j) * 64 + l;
    int r = ci >> 3, c = ci & 7;
    int cs = c ^ (r & 7);
    srcOffB[j]   = (bn * 256 + r) * 4096 + cs * 8;
    srcOffA32[j] = (bm * 256 + r) * 4096 + c * 8;
    dstSwzA[j]   = r * 64 + cs * 8;
  }
  const int ar = wm * 128 + (l & 15);
  const int br = wn * 64 + (l & 15);
  const int swz0 = (((l >> 4) + 0) ^ (l & 7)) * 8;
  const int swz1 = (((l >> 4) + 4) ^ (l & 7)) * 8;
  const int aoff0 = ar * 64 + swz0, aoff1 = ar * 64 + swz1;
  const int boff0 = 32768 + br * 64 + swz0, boff1 = 32768 + br * 64 + swz1;

  f32x4 acc[8][4];
#pragma unroll
  for (int mi = 0; mi < 8; ++mi)
#pragma unroll
    for (int ni = 0; ni < 4; ++ni) acc[mi][ni] = (f32x4){0.f, 0.f, 0.f, 0.f};

  auto STAGE = [&](int bufb, int kt) {
    const int kof = kt * 64;
#pragma unroll
    for (int j = 0; j < 4; ++j) {
      gld16(Wbf + srcOffB[j] + kof, &lds[32768 + bufb * 16384 + (w * 4 + j) * 512]);
      const float* p = Af32 + srcOffA32[j] + kof;
      f32x4 v0 = *(const f32x4*)p;
      f32x4 v1 = *(const f32x4*)(p + 4);
      bh8 o;
      o[0] = (short)f2bf(v0[0]); o[1] = (short)f2bf(v0[1]);
      o[2] = (short)f2bf(v0[2]); o[3] = (short)f2bf(v0[3]);
      o[4] = (short)f2bf(v1[0]); o[5] = (short)f2bf(v1[1]);
      o[6] = (short)f2bf(v1[2]); o[7] = (short)f2bf(v1[3]);
      *(bh8*)&lds[bufb * 16384 + dstSwzA[j]] = o;
    }
  };
  auto COMPUTE = [&](int bufb) {
    const int ab = bufb * 16384;
#pragma unroll
    for (int kk = 0; kk < 2; ++kk) {
      const int ao = ab + (kk ? aoff1 : aoff0);
      const int bo = ab + (kk ? boff1 : boff0);
      bh8 afr[8], bfr[4];
#pragma unroll
      for (int mi = 0; mi < 8; ++mi) afr[mi] = *(const bh8*)&lds[ao + mi * 1024];
#pragma unroll
      for (int ni = 0; ni < 4; ++ni) bfr[ni] = *(const bh8*)&lds[bo + ni * 1024];
#pragma unroll
      for (int mi = 0; mi < 8; ++mi)
#pragma unroll
        for (int ni = 0; ni < 4; ++ni)
          acc[mi][ni] = __builtin_amdgcn_mfma_f32_16x16x32_bf16(afr[mi], bfr[ni],
                                                                acc[mi][ni], 0, 0, 0);
    }
  };

  int buf = 0;
  STAGE(0, 0);
  __syncthreads();
  for (int kt = 0; kt < NT - 1; ++kt) {
    STAGE(buf ^ 1, kt + 1);
    COMPUTE(buf);
    __syncthreads();
    buf ^= 1;
  }
  COMPUTE(buf);

  const int col0 = bn * 256 + wn * 64 + (l & 15);
  const int row0 = bm * 256 + wm * 128 + (l >> 4) * 4;
#pragma unroll
  for (int ni = 0; ni < 4; ++ni) {
    float bv = bias[col0 + ni * 16];
#pragma unroll
    for (int mi = 0; mi < 8; ++mi) {
      size_t base = (size_t)(row0 + mi * 16) * 4096 + (size_t)(col0 + ni * 16);
#pragma unroll
      for (int rr = 0; rr < 4; ++rr)
        out[base + (size_t)rr * 4096] = acc[mi][ni][rr] + bv;
    }
  }
}

extern "C" void kernel_launch(void* const* d_in, const int* in_sizes, int n_in,
                              void* d_out, int out_size, void* d_ws, size_t ws_size,
                              hipStream_t stream) {
  const float* x    = (const float*)d_in[0];
  const int*   wq   = (const int*)d_in[1];
  const void*  wn   = d_in[2];
  const float* bias = (const float*)d_in[3];
  float*       out  = (float*)d_out;

  const size_t needA = (size_t)MDIM * KDIM * 2;
  const size_t needW = (size_t)NDIM * KDIM * 2;

  if (ws_size >= needA + needW) {
    u16* xbf = (u16*)d_ws;
    u16* wbf = (u16*)((char*)d_ws + needA);
    cvt_x<<<dim3(32768), dim3(256), 0, stream>>>(x, xbf);
    deq_w<<<dim3(4096), dim3(256), 0, stream>>>(wq, wn, wbf);
    gemm8<<<dim3(1024), dim3(512), 0, stream>>>(xbf, wbf, bias, out);
  } else if (ws_size >= needW) {
    u16* wbf = (u16*)d_ws;
    deq_w<<<dim3(4096), dim3(256), 0, stream>>>(wq, wn, wbf);
    gemm_fb<<<dim3(1024), dim3(512), 0, stream>>>(x, wbf, bias, out);
  }
}